// Round 8
// baseline (1295.276 us; speedup 1.0000x reference)
//
#include <hip/hip_runtime.h>
#include <hip/hip_bf16.h>
#include <cstdint>
#include <cstddef>

typedef unsigned short u16;
typedef __attribute__((ext_vector_type(8))) short bf16x8;
typedef __attribute__((ext_vector_type(4))) float f32x4;

// ---------- constants ----------
#define BB   64
#define SS   24
#define DD   300
#define DP   304     // padded K (bf16 rows)
#define HLS  512
#define BNN  16384   // 64*256
#define BEE  65536   // 64*1024
#define NAA  3000

// ---------- ws layout (bytes) ----------
static constexpr size_t O_COUNTS = 0;          // 16384*4
static constexpr size_t O_FILL   = 65536;      // 16384*4
static constexpr size_t O_ESUM   = 131072;     // 64*300*4
static constexpr size_t O_H0     = 207872;     // 64*512*4
static constexpr size_t O_C      = 338944;     // 64*512*4
static constexpr size_t Z_BYTES  = 470016;     // zero span
static constexpr size_t O_H1     = 470016;     // 64*512*4
static constexpr size_t O_XPROJ  = 601088;     // 1536*2048*4 (reused for Wt after LSTM)
static constexpr size_t O_BT_NODE = O_XPROJ;            // 512*304*2
static constexpr size_t O_BT_REL  = O_XPROJ + 311296;   // 512*304*2 (contiguous with BT_EDGE)
static constexpr size_t O_BT_EDGE = O_XPROJ + 622592;   // 384*304*2
static constexpr size_t O_NF     = 13184000;   // 16384*304*2
static constexpr size_t O_EF     = 23145472;   // 65536*304*2
static constexpr size_t O_HFEAT  = 62991360;   // 16384*512*2
static constexpr size_t O_RFEAT  = 79768576;   // 65536*512*2 (hosts packed W_hh during LSTM)
static constexpr size_t O_SSRC   = 146877440;  // 16384*4*4
static constexpr size_t O_SDST   = 147139584;
static constexpr size_t O_SE     = 147401728;  // 65536*4*4
static constexpr size_t O_SG     = 148450304;
static constexpr size_t O_DG     = 148712448;
static constexpr size_t O_RS     = 148974592;
static constexpr size_t O_ELIST  = 149040128;
static constexpr size_t O_LG     = 149302272;  // 65536*4*4
static constexpr size_t O_NOUT   = 150350848;  // 16384*512*2
static constexpr size_t O_NSUM   = 167128064;  // 64*512*4
static constexpr size_t O_QN     = 167259136;  // 64*512*4
static constexpr size_t O_QE     = 167390208;  // 64*300*4
static constexpr size_t O_QCAT   = 167467008;  // 64*1024*4
static constexpr size_t O_MID    = 167729152;  // 64*1536*4
// end = 168122368

// ---------- helpers ----------
__device__ __forceinline__ float bf(u16 u) {
  union { unsigned int i; float f; } c; c.i = ((unsigned int)u) << 16; return c.f;
}
__device__ __forceinline__ u16 f2bu(float f) {
  union { float f; unsigned int i; } c; c.f = f;
  unsigned int r = c.i + 0x7fffu + ((c.i >> 16) & 1u);
  return (u16)(r >> 16);
}

// ---------- trivial ----------
__global__ __launch_bounds__(256) void k_zero(float* __restrict__ p, int n) {
  int i = blockIdx.x * 256 + threadIdx.x, st = gridDim.x * 256;
  for (; i < n; i += st) p[i] = 0.f;
}

__global__ __launch_bounds__(256) void k_binit(const float* __restrict__ bias,
    const float* __restrict__ extra, float* __restrict__ out, int N, int ldo, int lde) {
  int col = blockIdx.x * 256 + threadIdx.x;
  int b = blockIdx.y;
  if (col < N) {
    float v = bias ? bias[col] : 0.f;
    if (extra) v += extra[(size_t)b * lde + col];
    out[(size_t)b * ldo + col] = v;
  }
}

// phrase features: 4 rows/block, 64 lanes/row; sum 4 f32 emb rows -> bf16 [row][304] zero-padded
__global__ __launch_bounds__(256) void k_feat(const int* __restrict__ toks, const float* __restrict__ emb,
                                              u16* __restrict__ outp) {
  int tid = threadIdx.x;
  int r = blockIdx.x * 4 + (tid >> 6);
  int lane = tid & 63;
  int t0 = toks[r * 4 + 0], t1 = toks[r * 4 + 1], t2 = toks[r * 4 + 2], t3 = toks[r * 4 + 3];
  const float* e0 = emb + (size_t)t0 * DD;
  const float* e1 = emb + (size_t)t1 * DD;
  const float* e2 = emb + (size_t)t2 * DD;
  const float* e3 = emb + (size_t)t3 * DD;
#pragma unroll
  for (int p = 0; p < 2; ++p) {
    int c = p * 256 + lane * 4;
    if (c >= DP) continue;
    ushort4 o;
    if (c + 3 < DD) {
      float4 a = *(const float4*)&e0[c], b4 = *(const float4*)&e1[c];
      float4 d = *(const float4*)&e2[c], e = *(const float4*)&e3[c];
      o.x = f2bu(a.x + b4.x + d.x + e.x);
      o.y = f2bu(a.y + b4.y + d.y + e.y);
      o.z = f2bu(a.z + b4.z + d.z + e.z);
      o.w = f2bu(a.w + b4.w + d.w + e.w);
    } else {
      o.x = o.y = o.z = o.w = 0;
    }
    *(ushort4*)&outp[(size_t)r * DP + c] = o;
  }
}

// transpose W f32 [K=300][N] -> Wt bf16 [Npad][304]; LDS 32x32 tiled
__global__ __launch_bounds__(256) void k_trans(const float* __restrict__ W, int N, int Npad,
                                               u16* __restrict__ Wt) {
  __shared__ float t[32][33];
  int tx = threadIdx.x & 31;
  int ty = threadIdx.x >> 5;
  int c0 = blockIdx.x * 32;
  int k0 = blockIdx.y * 32;
#pragma unroll
  for (int r = 0; r < 4; ++r) {
    int k = k0 + ty + r * 8;
    int c = c0 + tx;
    t[ty + r * 8][tx] = (k < DD && c < N) ? W[(size_t)k * N + c] : 0.f;
  }
  __syncthreads();
#pragma unroll
  for (int r = 0; r < 4; ++r) {
    int c = c0 + ty + r * 8;
    int k = k0 + tx;
    if (c < Npad && k < DP) Wt[(size_t)c * DP + k] = f2bu(t[tx][ty + r * 8]);
  }
}

// pack W_hh [k][g*512+j] -> Wp [k][j*4+g] (float4 per (k,j))
__global__ __launch_bounds__(256) void k_packW(const float* __restrict__ W, float* __restrict__ Wp) {
  int idx = blockIdx.x * 256 + threadIdx.x;   // k*512 + j
  int k = idx >> 9, j = idx & 511;
  float4 v;
  v.x = W[(size_t)k * 2048 + j];
  v.y = W[(size_t)k * 2048 + 512 + j];
  v.z = W[(size_t)k * 2048 + 1024 + j];
  v.w = W[(size_t)k * 2048 + 1536 + j];
  *(float4*)&Wp[(size_t)k * 2048 + j * 4] = v;
}

// ---------- f32 tiled GEMM (xproj only): C = gather(A)@W, gate-interleaved store ----------
__global__ __launch_bounds__(256) void gemm_f32(
    const float* __restrict__ A, int lda, const int* __restrict__ rowmap,
    const float* __restrict__ W, int N, int K, float* __restrict__ Cf, int gatepack) {
  __shared__ float As[32][128];
  __shared__ float Ws[32][128];
  int tid = threadIdx.x;
  int tx = tid & 15, ty = tid >> 4;
  int row0 = blockIdx.y * 128, col0 = blockIdx.x * 128;
  float acc[8][8];
#pragma unroll
  for (int i = 0; i < 8; ++i)
#pragma unroll
    for (int j = 0; j < 8; ++j) acc[i][j] = 0.f;
  for (int k0 = 0; k0 < K; k0 += 32) {
    for (int s = tid; s < 1024; s += 256) {
      int r = s >> 3, kc = (s & 7) << 2, kk = k0 + kc;
      float4 v = {0.f, 0.f, 0.f, 0.f};
      if (kk + 3 < K) {
        int ar = row0 + r;
        if (rowmap) ar = rowmap[ar];
        v = *(const float4*)&A[(size_t)ar * lda + kk];
      } else if (kk < K) {
        int ar = row0 + r;
        if (rowmap) ar = rowmap[ar];
        v.x = A[(size_t)ar * lda + kk];
        if (kk + 1 < K) v.y = A[(size_t)ar * lda + kk + 1];
        if (kk + 2 < K) v.z = A[(size_t)ar * lda + kk + 2];
      }
      As[kc + 0][r] = v.x; As[kc + 1][r] = v.y; As[kc + 2][r] = v.z; As[kc + 3][r] = v.w;
    }
    for (int s = tid; s < 1024; s += 256) {
      int kr = s >> 5, nc = (s & 31) << 2, kk = k0 + kr, col = col0 + nc;
      float4 wv = {0.f, 0.f, 0.f, 0.f};
      if (kk < K && col + 3 < N) wv = *(const float4*)&W[(size_t)kk * N + col];
      *(float4*)&Ws[kr][nc] = wv;
    }
    __syncthreads();
#pragma unroll 8
    for (int k = 0; k < 32; ++k) {
      float a[8], b[8];
      *(float4*)&a[0] = *(float4*)&As[k][ty * 8];
      *(float4*)&a[4] = *(float4*)&As[k][ty * 8 + 4];
      *(float4*)&b[0] = *(float4*)&Ws[k][tx * 8];
      *(float4*)&b[4] = *(float4*)&Ws[k][tx * 8 + 4];
#pragma unroll
      for (int i = 0; i < 8; ++i)
#pragma unroll
        for (int j = 0; j < 8; ++j) acc[i][j] = fmaf(a[i], b[j], acc[i][j]);
    }
    __syncthreads();
  }
#pragma unroll
  for (int i = 0; i < 8; ++i) {
    int gr = row0 + ty * 8 + i;
#pragma unroll
    for (int j = 0; j < 8; ++j) {
      int gc = col0 + tx * 8 + j;
      if (gc < N) {
        size_t oi = gatepack ? ((size_t)gr * 2048 + ((gc & 511) << 2) + (gc >> 9))
                             : ((size_t)gr * N + gc);
        Cf[oi] = acc[i][j];
      }
    }
  }
}

// ---------- unified A-resident MFMA GEMM ----------
// blocks [0,1024): ef rows (64/block), Bt=btrel(896 rows): tiles 0..3 -> rfeat + se; 4..6 -> esum
// blocks [1024,1280): nf rows, Bt=btnode(512 rows): tiles 0..3 -> hfeat + ssrc + sdst
__global__ __launch_bounds__(256) void gemm_feat(
    const u16* __restrict__ efA, const u16* __restrict__ nfA,
    const u16* __restrict__ btEF, const u16* __restrict__ btNF,
    u16* __restrict__ rfeat, u16* __restrict__ hfeat,
    const float* __restrict__ a_edge, const float* __restrict__ a_src, const float* __restrict__ a_dst,
    float* __restrict__ se, float* __restrict__ ssrc, float* __restrict__ sdst,
    float* __restrict__ esum) {
  __shared__ __align__(16) u16 Aa[64][328];                 // 41984 B, A panel resident
  __shared__ __align__(16) union {
    u16 Bs[2][128][40];                                     // 20480 B, B k-step dbuf
    float red[8][128];                                      // esum scratch
    float sered[2][64];                                     // se/ssrc scratch
  } S;

  int tid = threadIdx.x;
  int wave = tid >> 6, lane = tid & 63;
  int wr = wave >> 1, wc = wave & 1;
  int g = lane >> 4, rl = lane & 15;
  int kb = g * 8;

  bool isEF = blockIdx.x < 1024;
  int row0 = (isEF ? blockIdx.x : blockIdx.x - 1024) * 64;
  const u16* A  = isEF ? efA  : nfA;
  const u16* Bt = isEF ? btEF : btNF;
  u16* Cb = isEF ? rfeat : hfeat;
  const float* v1 = isEF ? a_edge : a_src;
  const float* v2 = isEF ? nullptr : a_dst;
  float* o1 = isEF ? se : ssrc;
  float* o2 = isEF ? nullptr : sdst;
  int NT = isEF ? 7 : 4;

  // stage A panel once: 64 rows x 328 cols (zeros beyond 304)
  for (int s = tid; s < 64 * 82; s += 256) {
    int r = s / 82, c4 = (s - r * 82) * 4;
    ushort4 v = {0, 0, 0, 0};
    if (c4 < DP) v = *(const ushort4*)&A[(size_t)(row0 + r) * DP + c4];
    *(ushort4*)&Aa[r][c4] = v;
  }

#define STAGE_B(bufv, k0v)                                              \
  for (int s = tid; s < 1024; s += 256) {                               \
    int rr = s >> 3, kc = (s & 7) << 2, kk = (k0v) + kc;                \
    ushort4 vb = {0, 0, 0, 0};                                          \
    if (kk < DP) vb = *(const ushort4*)&Bt[(size_t)(col0 + rr) * DP + kk]; \
    *(ushort4*)&S.Bs[bufv][rr][kc] = vb;                                \
  }

  for (int ct = 0; ct < NT; ++ct) {
    int col0 = ct * 128;
    f32x4 acc[2][4];
#pragma unroll
    for (int i = 0; i < 2; ++i)
#pragma unroll
      for (int j = 0; j < 4; ++j) acc[i][j] = (f32x4){0.f, 0.f, 0.f, 0.f};

    STAGE_B(0, 0)
    __syncthreads();   // first ct: also covers Aa staging
    for (int ks = 0; ks < 10; ++ks) {
      if (ks < 9) { STAGE_B((ks + 1) & 1, (ks + 1) * 32) }
      int k0 = ks * 32, buf = ks & 1;
      bf16x8 af[2], bfr[4];
      af[0] = *(const bf16x8*)&Aa[wr * 32 + rl][k0 + kb];
      af[1] = *(const bf16x8*)&Aa[wr * 32 + 16 + rl][k0 + kb];
#pragma unroll
      for (int j = 0; j < 4; ++j)
        bfr[j] = *(const bf16x8*)&S.Bs[buf][wc * 64 + j * 16 + rl][kb];
#pragma unroll
      for (int i = 0; i < 2; ++i)
#pragma unroll
        for (int j = 0; j < 4; ++j)
          acc[i][j] = __builtin_amdgcn_mfma_f32_16x16x32_bf16(af[i], bfr[j], acc[i][j], 0, 0, 0);
      __syncthreads();
    }

    if (ct < 4) {
      // store C tile (bf16)
#pragma unroll
      for (int i = 0; i < 2; ++i)
#pragma unroll
        for (int j = 0; j < 4; ++j) {
          int gc = col0 + wc * 64 + j * 16 + rl;
#pragma unroll
          for (int reg = 0; reg < 4; ++reg) {
            int gr = row0 + wr * 32 + i * 16 + g * 4 + reg;
            Cb[(size_t)gr * 512 + gc] = f2bu(acc[i][j][reg]);
          }
        }
      // per-row dot with v1 (and v2 for nf) over this head's 128 cols
      int npass = v2 ? 2 : 1;
      for (int pass = 0; pass < npass; ++pass) {
        const float* v = pass ? v2 : v1;
        float ce[4];
#pragma unroll
        for (int j = 0; j < 4; ++j) ce[j] = v[col0 + wc * 64 + j * 16 + rl];
        float p[2][4];
#pragma unroll
        for (int i = 0; i < 2; ++i)
#pragma unroll
          for (int reg = 0; reg < 4; ++reg) {
            float s = 0.f;
#pragma unroll
            for (int j = 0; j < 4; ++j) s += acc[i][j][reg] * ce[j];
            p[i][reg] = s;
          }
#pragma unroll
        for (int m = 1; m < 16; m <<= 1)
#pragma unroll
          for (int i = 0; i < 2; ++i)
#pragma unroll
            for (int reg = 0; reg < 4; ++reg)
              p[i][reg] += __shfl_xor(p[i][reg], m);
        if (rl == 0) {
#pragma unroll
          for (int i = 0; i < 2; ++i)
#pragma unroll
            for (int reg = 0; reg < 4; ++reg)
              S.sered[wc][wr * 32 + i * 16 + g * 4 + reg] = p[i][reg];
        }
        __syncthreads();
        if (tid < 64) {
          float* o = pass ? o2 : o1;
          o[(size_t)(row0 + tid) * 4 + ct] = S.sered[0][tid] + S.sered[1][tid];
        }
        __syncthreads();
      }
    } else {
      // ef tiles 4..6: relu + per-batch column sums -> esum
#pragma unroll
      for (int j = 0; j < 4; ++j) {
        float s = 0.f;
#pragma unroll
        for (int i = 0; i < 2; ++i)
#pragma unroll
          for (int reg = 0; reg < 4; ++reg) s += fmaxf(acc[i][j][reg], 0.f);
        S.red[wr * 4 + g][wc * 64 + j * 16 + rl] = s;
      }
      __syncthreads();
      if (tid < 128) {
        float s = 0.f;
#pragma unroll
        for (int y = 0; y < 8; ++y) s += S.red[y][tid];
        int c = col0 - 512 + tid;
        if (c < 300) atomicAdd(&esum[(size_t)(row0 >> 10) * 300 + c], s);
      }
      __syncthreads();
    }
  }
#undef STAGE_B
}

// ---------- small-M GEMM (M=64): out += A[64][K] @ W[K][N], split-K atomics ----------
__global__ __launch_bounds__(256) void gemm_small(
    const float* __restrict__ A, int lda, const float* __restrict__ W,
    int N, int K, int ldo, float* __restrict__ out) {
  __shared__ float As[64][256];
  int tid = threadIdx.x;
  int k0 = blockIdx.y * 256;
  int kt = min(256, K - k0);
  int col = blockIdx.x * 64 + (tid & 63);
  int bg = tid >> 6;
  int nseg = kt >> 2;
  for (int s = tid; s < 64 * nseg; s += 256) {
    int r = s / nseg, kq = s - r * nseg;
    *(float4*)&As[r][kq << 2] = *(const float4*)&A[(size_t)r * lda + k0 + (kq << 2)];
  }
  __syncthreads();
  float acc[16];
#pragma unroll
  for (int i = 0; i < 16; ++i) acc[i] = 0.f;
  if (col < N) {
    for (int k = 0; k < kt; k += 4) {
      float w0 = W[(size_t)(k0 + k) * N + col];
      float w1 = W[(size_t)(k0 + k + 1) * N + col];
      float w2 = W[(size_t)(k0 + k + 2) * N + col];
      float w3 = W[(size_t)(k0 + k + 3) * N + col];
#pragma unroll
      for (int bi = 0; bi < 16; ++bi) {
        float4 a4 = *(const float4*)&As[bg * 16 + bi][k];
        acc[bi] = fmaf(a4.x, w0, fmaf(a4.y, w1, fmaf(a4.z, w2, fmaf(a4.w, w3, acc[bi]))));
      }
    }
#pragma unroll
    for (int bi = 0; bi < 16; ++bi)
      atomicAdd(&out[(size_t)(bg * 16 + bi) * ldo + col], acc[bi]);
  }
}

// ---------- LSTM step (packed W; 128-thread blocks, 256 blocks fill all CUs) ----------
__global__ __launch_bounds__(128) void k_lstm3(
    const float* __restrict__ Wp, const float* __restrict__ xproj,
    const float* __restrict__ bls, const int* __restrict__ qmask,
    const float* __restrict__ h_in, float* __restrict__ h_out, float* __restrict__ c, int t) {
  __shared__ float hs[4][512];
  int tid = threadIdx.x;
  int j = blockIdx.x * 32 + (tid & 31);
  int bq = tid >> 5;                        // 0..3
  int b = blockIdx.y * 4 + bq;
  for (int i = tid; i < 2048; i += 128)
    hs[i >> 9][i & 511] = h_in[(size_t)(blockIdx.y * 4 + (i >> 9)) * 512 + (i & 511)];
  __syncthreads();
  float a0 = 0.f, a1 = 0.f, a2 = 0.f, a3 = 0.f;
#pragma unroll 8
  for (int k = 0; k < 512; ++k) {
    float hv = hs[bq][k];
    float4 w = *(const float4*)&Wp[(size_t)k * 2048 + j * 4];
    a0 = fmaf(hv, w.x, a0);
    a1 = fmaf(hv, w.y, a1);
    a2 = fmaf(hv, w.z, a2);
    a3 = fmaf(hv, w.w, a3);
  }
  size_t xb = ((size_t)b * SS + t) * 2048;
  float4 xp = *(const float4*)&xproj[xb + j * 4];
  float gi = a0 + xp.x + bls[j];
  float gf = a1 + xp.y + bls[512 + j];
  float gg = a2 + xp.z + bls[1024 + j];
  float go = a3 + xp.w + bls[1536 + j];
  float si = 1.f / (1.f + __expf(-gi));
  float sf = 1.f / (1.f + __expf(-gf));
  float so = 1.f / (1.f + __expf(-go));
  float tg = 2.f / (1.f + __expf(-2.f * gg)) - 1.f;
  int idx = b * 512 + j;
  float cold = c[idx];
  float cn = sf * cold + si * tg;
  float hn = so * (2.f / (1.f + __expf(-2.f * cn)) - 1.f);
  if (qmask[b * SS + t] > 0) { c[idx] = cn; h_out[idx] = hn; }
  else h_out[idx] = h_in[idx];
}

// ---------- CSR ----------
__global__ __launch_bounds__(256) void k_prep(const int* __restrict__ src, const int* __restrict__ dst,
    int* __restrict__ sg, int* __restrict__ dg, int* __restrict__ counts) {
  int i = blockIdx.x * 256 + threadIdx.x;
  int b = i >> 10;
  sg[i] = (b << 8) + src[i];
  int dgl = (b << 8) + dst[i];
  dg[i] = dgl;
  atomicAdd(&counts[dgl], 1);
}

__global__ __launch_bounds__(256) void k_scan(const int* __restrict__ counts, int* __restrict__ rs) {
  __shared__ int sc[256];
  int b = blockIdx.x, tid = threadIdx.x;
  int v = counts[b * 256 + tid];
  sc[tid] = v;
  __syncthreads();
  for (int off = 1; off < 256; off <<= 1) {
    int add = (tid >= off) ? sc[tid - off] : 0;
    __syncthreads();
    sc[tid] += add;
    __syncthreads();
  }
  rs[b * 256 + tid] = b * 1024 + sc[tid] - v;
}

__global__ __launch_bounds__(256) void k_scatter(const int* __restrict__ dg, const int* __restrict__ rs,
    int* __restrict__ fill, int* __restrict__ elist) {
  int i = blockIdx.x * 256 + threadIdx.x;
  int d = dg[i];
  int pos = rs[d] + atomicAdd(&fill[d], 1);
  elist[pos] = i;
}

// ---------- logits / softmax / aggregate ----------
__global__ __launch_bounds__(256) void k_logit(const int* __restrict__ sg, const int* __restrict__ dg,
    const float* __restrict__ ssrc, const float* __restrict__ sdst,
    const float* __restrict__ se, float* __restrict__ lg) {
  int i = blockIdx.x * 256 + threadIdx.x;
  int e = i >> 2, h = i & 3;
  float x = ssrc[sg[e] * 4 + h] + sdst[dg[e] * 4 + h] + se[i];
  lg[i] = x > 0.f ? x : 0.2f * x;
}

__global__ __launch_bounds__(256) void k_soft(const int* __restrict__ counts, const int* __restrict__ rs,
    const int* __restrict__ elist, float* __restrict__ lg) {
  int id = blockIdx.x * 256 + threadIdx.x;
  int n = id >> 2, h = id & 3;
  int deg = counts[n];
  if (deg == 0) return;
  int st = rs[n];
  float m = -1e30f;
  for (int i = 0; i < deg; ++i) { int e = elist[st + i]; m = fmaxf(m, lg[e * 4 + h]); }
  float s = 0.f;
  for (int i = 0; i < deg; ++i) {
    int e = elist[st + i];
    float p = __expf(lg[e * 4 + h] - m);
    lg[e * 4 + h] = p;
    s += p;
  }
  float inv = 1.f / (s + 1e-9f);
  for (int i = 0; i < deg; ++i) { int e = elist[st + i]; lg[e * 4 + h] *= inv; }
}

__global__ __launch_bounds__(256) void k_agg(const int* __restrict__ counts, const int* __restrict__ rs,
    const int* __restrict__ elist, const int* __restrict__ sg, const float* __restrict__ lg,
    const u16* __restrict__ hfeat, const u16* __restrict__ rfeat, u16* __restrict__ nout) {
  int n = blockIdx.x;
  int deg = counts[n], st = rs[n];
  int c1 = threadIdx.x, c2 = threadIdx.x + 256;
  float a1 = 0.f, a2 = 0.f;
  for (int i = 0; i < deg; ++i) {
    int e = elist[st + i];
    int s = sg[e];
    float al1 = lg[e * 4 + (c1 >> 7)], al2 = lg[e * 4 + (c2 >> 7)];
    a1 += al1 * (bf(hfeat[(size_t)s * 512 + c1]) + bf(rfeat[(size_t)e * 512 + c1]));
    a2 += al2 * (bf(hfeat[(size_t)s * 512 + c2]) + bf(rfeat[(size_t)e * 512 + c2]));
  }
  a1 = a1 > 0.f ? a1 : __expf(a1) - 1.f;
  a2 = a2 > 0.f ? a2 : __expf(a2) - 1.f;
  nout[(size_t)n * 512 + c1] = f2bu(a1);
  nout[(size_t)n * 512 + c2] = f2bu(a2);
}

__global__ __launch_bounds__(512) void k_nodesum(const u16* __restrict__ nout, float* __restrict__ nsum) {
  int b = blockIdx.x, col = threadIdx.x;
  float s = 0.f;
  for (int n = 0; n < 256; ++n) s += bf(nout[(size_t)((b << 8) + n) * 512 + col]);
  nsum[b * 512 + col] = s;
}

// ---------- launch ----------
extern "C" void kernel_launch(void* const* d_in, const int* in_sizes, int n_in,
                              void* d_out, int out_size, void* d_ws, size_t ws_size,
                              hipStream_t stream) {
  const int*   question   = (const int*)d_in[0];
  const int*   qmask      = (const int*)d_in[1];
  const int*   node_toks  = (const int*)d_in[2];
  const int*   edge_toks  = (const int*)d_in[3];
  const int*   src_ids    = (const int*)d_in[4];
  const int*   dst_ids    = (const int*)d_in[5];
  const float* word_emb   = (const float*)d_in[6];
  const float* W_ih       = (const float*)d_in[7];
  const float* W_hh       = (const float*)d_in[8];
  const float* b_lstm     = (const float*)d_in[9];
  const float* W_node     = (const float*)d_in[10];
  const float* W_rel      = (const float*)d_in[11];
  const float* a_src      = (const float*)d_in[12];
  const float* a_dst      = (const float*)d_in[13];
  const float* a_edge     = (const float*)d_in[14];
  const float* W_edge_upd = (const float*)d_in[15];
  const float* W_qnode    = (const float*)d_in[16];
  const float* b_qnode    = (const float*)d_in[17];
  const float* W_qedge    = (const float*)d_in[18];
  const float* b_qedge    = (const float*)d_in[19];
  const float* W_edge_prj = (const float*)d_in[20];
  const float* b_edge_prj = (const float*)d_in[21];
  const float* W_mid      = (const float*)d_in[22];
  const float* b_mid      = (const float*)d_in[23];
  const float* W_pre      = (const float*)d_in[24];
  const float* b_pre      = (const float*)d_in[25];
  float* outp = (float*)d_out;

  char* ws = (char*)d_ws;
  int*   counts = (int*)(ws + O_COUNTS);
  int*   fill   = (int*)(ws + O_FILL);
  float* esum   = (float*)(ws + O_ESUM);
  float* h0     = (float*)(ws + O_H0);
  float* cst    = (float*)(ws + O_C);
  float* h1     = (float*)(ws + O_H1);
  float* xproj  = (float*)(ws + O_XPROJ);
  u16*   btn    = (u16*)(ws + O_BT_NODE);
  u16*   btr    = (u16*)(ws + O_BT_REL);
  u16*   bte    = (u16*)(ws + O_BT_EDGE);
  u16*   nf     = (u16*)(ws + O_NF);
  u16*   ef     = (u16*)(ws + O_EF);
  u16*   hfeat  = (u16*)(ws + O_HFEAT);
  u16*   rfeat  = (u16*)(ws + O_RFEAT);
  float* Wp     = (float*)(ws + O_RFEAT);   // packed W_hh, dead before rfeat is written
  float* ssrc   = (float*)(ws + O_SSRC);
  float* sdst   = (float*)(ws + O_SDST);
  float* se     = (float*)(ws + O_SE);
  int*   sg     = (int*)(ws + O_SG);
  int*   dg     = (int*)(ws + O_DG);
  int*   rs     = (int*)(ws + O_RS);
  int*   elist  = (int*)(ws + O_ELIST);
  float* lg     = (float*)(ws + O_LG);
  u16*   nout   = (u16*)(ws + O_NOUT);
  float* nsum   = (float*)(ws + O_NSUM);
  float* qn     = (float*)(ws + O_QN);
  float* qe     = (float*)(ws + O_QE);
  float* qcat   = (float*)(ws + O_QCAT);
  float* midb   = (float*)(ws + O_MID);

  // 1. zero accumulator span
  k_zero<<<128, 256, 0, stream>>>((float*)ws, (int)(Z_BYTES / 4));
  // 2. phrase features
  k_feat<<<BNN / 4, 256, 0, stream>>>(node_toks, word_emb, nf);
  k_feat<<<BEE / 4, 256, 0, stream>>>(edge_toks, word_emb, ef);
  // 3. pack W_hh; xproj = emb(question) @ W_ih (gate-interleaved)
  k_packW<<<1024, 256, 0, stream>>>(W_hh, Wp);
  gemm_f32<<<dim3(16, 12), 256, 0, stream>>>(word_emb, DD, question, W_ih, 2048, DD, xproj, 1);
  // 4. LSTM (final h in h0)
  for (int t = 0; t < SS; ++t) {
    const float* hin = (t & 1) ? h1 : h0;
    float* hout = (t & 1) ? h0 : h1;
    k_lstm3<<<dim3(16, 16), 128, 0, stream>>>(Wp, xproj, b_lstm, qmask, hin, hout, cst, t);
  }
  // 5. weight transposes
  k_trans<<<dim3(16, 10), 256, 0, stream>>>(W_node, 512, 512, btn);
  k_trans<<<dim3(16, 10), 256, 0, stream>>>(W_rel, 512, 512, btr);
  k_trans<<<dim3(12, 10), 256, 0, stream>>>(W_edge_upd, 300, 384, bte);
  // 6. unified A-resident MFMA GEMM: ef->rfeat+se+esum, nf->hfeat+ssrc+sdst
  gemm_feat<<<1280, 256, 0, stream>>>(ef, nf, btr, btn, rfeat, hfeat,
                                      a_edge, a_src, a_dst, se, ssrc, sdst, esum);
  // 7. CSR by dst
  k_prep<<<256, 256, 0, stream>>>(src_ids, dst_ids, sg, dg, counts);
  k_scan<<<64, 256, 0, stream>>>(counts, rs);
  k_scatter<<<256, 256, 0, stream>>>(dg, rs, fill, elist);
  // 8. logits -> softmax -> aggregate
  k_logit<<<1024, 256, 0, stream>>>(sg, dg, ssrc, sdst, se, lg);
  k_soft<<<256, 256, 0, stream>>>(counts, rs, elist, lg);
  k_agg<<<BNN, 256, 0, stream>>>(counts, rs, elist, sg, lg, hfeat, rfeat, nout);
  k_nodesum<<<64, 512, 0, stream>>>(nout, nsum);
  // 9. fusion head
  k_binit<<<dim3(2, 64), 256, 0, stream>>>(b_qnode, nsum, qn, 512, 512, 512);
  k_binit<<<dim3(2, 64), 256, 0, stream>>>(b_qedge, esum, qe, 300, 300, 300);
  gemm_small<<<dim3(8, 2), 256, 0, stream>>>(h0, 512, W_qnode, 512, 512, 512, qn);
  gemm_small<<<dim3(5, 2), 256, 0, stream>>>(h0, 512, W_qedge, 300, 512, 300, qe);
  k_binit<<<dim3(2, 64), 256, 0, stream>>>(b_edge_prj, nullptr, qcat, 512, 1024, 0);
  k_binit<<<dim3(2, 64), 256, 0, stream>>>(nullptr, qn, qcat + 512, 512, 1024, 512);
  gemm_small<<<dim3(8, 2), 256, 0, stream>>>(qe, 300, W_edge_prj, 512, 300, 1024, qcat);
  k_binit<<<dim3(6, 64), 256, 0, stream>>>(b_mid, nullptr, midb, 1536, 1536, 0);
  gemm_small<<<dim3(24, 4), 256, 0, stream>>>(qcat, 1024, W_mid, 1536, 1024, 1536, midb);
  k_binit<<<dim3(12, 64), 256, 0, stream>>>(b_pre, nullptr, outp, NAA, NAA, 0);
  gemm_small<<<dim3(47, 6), 256, 0, stream>>>(midb, 1536, W_pre, NAA, 1536, NAA, outp);
}

// Round 9
// 1144.479 us; speedup vs baseline: 1.1318x; 1.1318x over previous
//
#include <hip/hip_runtime.h>
#include <hip/hip_bf16.h>
#include <cstdint>
#include <cstddef>

typedef unsigned short u16;
typedef __attribute__((ext_vector_type(8))) short bf16x8;
typedef __attribute__((ext_vector_type(4))) float f32x4;

// ---------- constants ----------
#define BB   64
#define SS   24
#define DD   300
#define DP   304     // padded K (bf16 rows)
#define HLS  512
#define BNN  16384   // 64*256
#define BEE  65536   // 64*1024
#define NAA  3000

// ---------- ws layout (bytes) ----------
static constexpr size_t O_COUNTS = 0;          // 16384*4
static constexpr size_t O_FILL   = 65536;      // 16384*4
static constexpr size_t O_ESUM   = 131072;     // 64*300*4
static constexpr size_t O_H0     = 207872;     // 64*512*4
static constexpr size_t O_C      = 338944;     // 64*512*4
static constexpr size_t Z_BYTES  = 470016;     // zero span
static constexpr size_t O_H1     = 470016;     // 64*512*4
static constexpr size_t O_XPROJ  = 601088;     // 1536*2048*4 (reused for Wt after LSTM)
static constexpr size_t O_BT_NODE = O_XPROJ;            // 512*304*2
static constexpr size_t O_BT_REL  = O_XPROJ + 311296;   // 512*304*2 (contiguous with BT_EDGE)
static constexpr size_t O_BT_EDGE = O_XPROJ + 622592;   // 384*304*2
static constexpr size_t O_NF     = 13184000;   // 16384*304*2
static constexpr size_t O_EF     = 23145472;   // 65536*304*2
static constexpr size_t O_HFEAT  = 62991360;   // 16384*512*2
static constexpr size_t O_RFEAT  = 79768576;   // 65536*512*2 (hosts packed W_hh during LSTM)
static constexpr size_t O_SSRC   = 146877440;  // 16384*4*4
static constexpr size_t O_SDST   = 147139584;
static constexpr size_t O_SE     = 147401728;  // 65536*4*4
static constexpr size_t O_SG     = 148450304;
static constexpr size_t O_DG     = 148712448;
static constexpr size_t O_RS     = 148974592;
static constexpr size_t O_ELIST  = 149040128;
static constexpr size_t O_LG     = 149302272;  // 65536*4*4
static constexpr size_t O_NOUT   = 150350848;  // 16384*512*2
static constexpr size_t O_NSUM   = 167128064;  // 64*512*4
static constexpr size_t O_QN     = 167259136;  // 64*512*4
static constexpr size_t O_QE     = 167390208;  // 64*300*4
static constexpr size_t O_QCAT   = 167467008;  // 64*1024*4
static constexpr size_t O_MID    = 167729152;  // 64*1536*4
// end = 168122368

// ---------- helpers ----------
__device__ __forceinline__ float bf(u16 u) {
  union { unsigned int i; float f; } c; c.i = ((unsigned int)u) << 16; return c.f;
}
__device__ __forceinline__ u16 f2bu(float f) {
  union { float f; unsigned int i; } c; c.f = f;
  unsigned int r = c.i + 0x7fffu + ((c.i >> 16) & 1u);
  return (u16)(r >> 16);
}

// ---------- trivial ----------
__global__ __launch_bounds__(256) void k_zero(float* __restrict__ p, int n) {
  int i = blockIdx.x * 256 + threadIdx.x, st = gridDim.x * 256;
  for (; i < n; i += st) p[i] = 0.f;
}

__global__ __launch_bounds__(256) void k_binit(const float* __restrict__ bias,
    const float* __restrict__ extra, float* __restrict__ out, int N, int ldo, int lde) {
  int col = blockIdx.x * 256 + threadIdx.x;
  int b = blockIdx.y;
  if (col < N) {
    float v = bias ? bias[col] : 0.f;
    if (extra) v += extra[(size_t)b * lde + col];
    out[(size_t)b * ldo + col] = v;
  }
}

// phrase features: 4 rows/block, 64 lanes/row; sum 4 f32 emb rows -> bf16 [row][304] zero-padded
__global__ __launch_bounds__(256) void k_feat(const int* __restrict__ toks, const float* __restrict__ emb,
                                              u16* __restrict__ outp) {
  int tid = threadIdx.x;
  int r = blockIdx.x * 4 + (tid >> 6);
  int lane = tid & 63;
  int t0 = toks[r * 4 + 0], t1 = toks[r * 4 + 1], t2 = toks[r * 4 + 2], t3 = toks[r * 4 + 3];
  const float* e0 = emb + (size_t)t0 * DD;
  const float* e1 = emb + (size_t)t1 * DD;
  const float* e2 = emb + (size_t)t2 * DD;
  const float* e3 = emb + (size_t)t3 * DD;
#pragma unroll
  for (int p = 0; p < 2; ++p) {
    int c = p * 256 + lane * 4;
    if (c >= DP) continue;
    ushort4 o;
    if (c + 3 < DD) {
      float4 a = *(const float4*)&e0[c], b4 = *(const float4*)&e1[c];
      float4 d = *(const float4*)&e2[c], e = *(const float4*)&e3[c];
      o.x = f2bu(a.x + b4.x + d.x + e.x);
      o.y = f2bu(a.y + b4.y + d.y + e.y);
      o.z = f2bu(a.z + b4.z + d.z + e.z);
      o.w = f2bu(a.w + b4.w + d.w + e.w);
    } else {
      o.x = o.y = o.z = o.w = 0;
    }
    *(ushort4*)&outp[(size_t)r * DP + c] = o;
  }
}

// transpose W f32 [K=300][N] -> Wt bf16 [Npad][304]; LDS 32x32 tiled
__global__ __launch_bounds__(256) void k_trans(const float* __restrict__ W, int N, int Npad,
                                               u16* __restrict__ Wt) {
  __shared__ float t[32][33];
  int tx = threadIdx.x & 31;
  int ty = threadIdx.x >> 5;
  int c0 = blockIdx.x * 32;
  int k0 = blockIdx.y * 32;
#pragma unroll
  for (int r = 0; r < 4; ++r) {
    int k = k0 + ty + r * 8;
    int c = c0 + tx;
    t[ty + r * 8][tx] = (k < DD && c < N) ? W[(size_t)k * N + c] : 0.f;
  }
  __syncthreads();
#pragma unroll
  for (int r = 0; r < 4; ++r) {
    int c = c0 + ty + r * 8;
    int k = k0 + tx;
    if (c < Npad && k < DP) Wt[(size_t)c * DP + k] = f2bu(t[tx][ty + r * 8]);
  }
}

// pack W_hh [k][g*512+j] -> Wp [k][j*4+g] (float4 per (k,j))
__global__ __launch_bounds__(256) void k_packW(const float* __restrict__ W, float* __restrict__ Wp) {
  int idx = blockIdx.x * 256 + threadIdx.x;   // k*512 + j
  int k = idx >> 9, j = idx & 511;
  float4 v;
  v.x = W[(size_t)k * 2048 + j];
  v.y = W[(size_t)k * 2048 + 512 + j];
  v.z = W[(size_t)k * 2048 + 1024 + j];
  v.w = W[(size_t)k * 2048 + 1536 + j];
  *(float4*)&Wp[(size_t)k * 2048 + j * 4] = v;
}

// ---------- f32 tiled GEMM (xproj only): C = gather(A)@W, gate-interleaved store ----------
__global__ __launch_bounds__(256) void gemm_f32(
    const float* __restrict__ A, int lda, const int* __restrict__ rowmap,
    const float* __restrict__ W, int N, int K, float* __restrict__ Cf, int gatepack) {
  __shared__ float As[32][128];
  __shared__ float Ws[32][128];
  int tid = threadIdx.x;
  int tx = tid & 15, ty = tid >> 4;
  int row0 = blockIdx.y * 128, col0 = blockIdx.x * 128;
  float acc[8][8];
#pragma unroll
  for (int i = 0; i < 8; ++i)
#pragma unroll
    for (int j = 0; j < 8; ++j) acc[i][j] = 0.f;
  for (int k0 = 0; k0 < K; k0 += 32) {
    for (int s = tid; s < 1024; s += 256) {
      int r = s >> 3, kc = (s & 7) << 2, kk = k0 + kc;
      float4 v = {0.f, 0.f, 0.f, 0.f};
      if (kk + 3 < K) {
        int ar = row0 + r;
        if (rowmap) ar = rowmap[ar];
        v = *(const float4*)&A[(size_t)ar * lda + kk];
      } else if (kk < K) {
        int ar = row0 + r;
        if (rowmap) ar = rowmap[ar];
        v.x = A[(size_t)ar * lda + kk];
        if (kk + 1 < K) v.y = A[(size_t)ar * lda + kk + 1];
        if (kk + 2 < K) v.z = A[(size_t)ar * lda + kk + 2];
      }
      As[kc + 0][r] = v.x; As[kc + 1][r] = v.y; As[kc + 2][r] = v.z; As[kc + 3][r] = v.w;
    }
    for (int s = tid; s < 1024; s += 256) {
      int kr = s >> 5, nc = (s & 31) << 2, kk = k0 + kr, col = col0 + nc;
      float4 wv = {0.f, 0.f, 0.f, 0.f};
      if (kk < K && col + 3 < N) wv = *(const float4*)&W[(size_t)kk * N + col];
      *(float4*)&Ws[kr][nc] = wv;
    }
    __syncthreads();
#pragma unroll 8
    for (int k = 0; k < 32; ++k) {
      float a[8], b[8];
      *(float4*)&a[0] = *(float4*)&As[k][ty * 8];
      *(float4*)&a[4] = *(float4*)&As[k][ty * 8 + 4];
      *(float4*)&b[0] = *(float4*)&Ws[k][tx * 8];
      *(float4*)&b[4] = *(float4*)&Ws[k][tx * 8 + 4];
#pragma unroll
      for (int i = 0; i < 8; ++i)
#pragma unroll
        for (int j = 0; j < 8; ++j) acc[i][j] = fmaf(a[i], b[j], acc[i][j]);
    }
    __syncthreads();
  }
#pragma unroll
  for (int i = 0; i < 8; ++i) {
    int gr = row0 + ty * 8 + i;
#pragma unroll
    for (int j = 0; j < 8; ++j) {
      int gc = col0 + tx * 8 + j;
      if (gc < N) {
        size_t oi = gatepack ? ((size_t)gr * 2048 + ((gc & 511) << 2) + (gc >> 9))
                             : ((size_t)gr * N + gc);
        Cf[oi] = acc[i][j];
      }
    }
  }
}

// ---------- unified A-resident MFMA GEMM, B from global (L2-resident) ----------
// blocks [0,1024): ef rows (64/block), Bt=btrel(896 rows): tiles 0..3 -> rfeat + se; 4..6 -> esum
// blocks [1024,1280): nf rows, Bt=btnode(512 rows): tiles 0..3 -> hfeat + ssrc + sdst
// k-loop has NO barriers: A is LDS-read-only after one sync; B frags load straight
// from global (whole B = 545 KB, read by every block -> L2-resident).
__global__ __launch_bounds__(256) void gemm_feat(
    const u16* __restrict__ efA, const u16* __restrict__ nfA,
    const u16* __restrict__ btEF, const u16* __restrict__ btNF,
    u16* __restrict__ rfeat, u16* __restrict__ hfeat,
    const float* __restrict__ a_edge, const float* __restrict__ a_src, const float* __restrict__ a_dst,
    float* __restrict__ se, float* __restrict__ ssrc, float* __restrict__ sdst,
    float* __restrict__ esum) {
  __shared__ __align__(16) u16 Aa[64][328];   // 41984 B, A panel resident
  __shared__ float sered[2][64];
  __shared__ float red[8][128];               // total LDS ~46.6 KB -> 3 blocks/CU

  int tid = threadIdx.x;
  int wave = tid >> 6, lane = tid & 63;
  int wr = wave >> 1, wc = wave & 1;
  int g = lane >> 4, rl = lane & 15;
  int kb = g * 8;

  bool isEF = blockIdx.x < 1024;
  int row0 = (isEF ? blockIdx.x : blockIdx.x - 1024) * 64;
  const u16* A  = isEF ? efA  : nfA;
  const u16* Bt = isEF ? btEF : btNF;
  u16* Cb = isEF ? rfeat : hfeat;
  const float* v1 = isEF ? a_edge : a_src;
  const float* v2 = isEF ? nullptr : a_dst;
  float* o1 = isEF ? se : ssrc;
  float* o2 = isEF ? nullptr : sdst;
  int NT = isEF ? 7 : 4;

  // stage A panel once: 64 rows x 328 cols (zeros beyond 304)
  for (int s = tid; s < 64 * 82; s += 256) {
    int r = s / 82, c4 = (s - r * 82) * 4;
    ushort4 v = {0, 0, 0, 0};
    if (c4 < DP) v = *(const ushort4*)&A[(size_t)(row0 + r) * DP + c4];
    *(ushort4*)&Aa[r][c4] = v;
  }
  __syncthreads();

  for (int ct = 0; ct < NT; ++ct) {
    int col0 = ct * 128;
    f32x4 acc[2][4];
#pragma unroll
    for (int i = 0; i < 2; ++i)
#pragma unroll
      for (int j = 0; j < 4; ++j) acc[i][j] = (f32x4){0.f, 0.f, 0.f, 0.f};

    // per-lane B row base pointers (each lane owns 4 B rows for this col-tile)
    const u16* bp0 = Bt + (size_t)(col0 + wc * 64 + 0 * 16 + rl) * DP + kb;
    const u16* bp1 = Bt + (size_t)(col0 + wc * 64 + 1 * 16 + rl) * DP + kb;
    const u16* bp2 = Bt + (size_t)(col0 + wc * 64 + 2 * 16 + rl) * DP + kb;
    const u16* bp3 = Bt + (size_t)(col0 + wc * 64 + 3 * 16 + rl) * DP + kb;

#pragma unroll
    for (int ks = 0; ks < 10; ++ks) {
      int k0 = ks * 32;
      bf16x8 bfr[4];
      bfr[0] = *(const bf16x8*)&bp0[k0];
      bfr[1] = *(const bf16x8*)&bp1[k0];
      bfr[2] = *(const bf16x8*)&bp2[k0];
      bfr[3] = *(const bf16x8*)&bp3[k0];
      bf16x8 af0 = *(const bf16x8*)&Aa[wr * 32 + rl][k0 + kb];
      bf16x8 af1 = *(const bf16x8*)&Aa[wr * 32 + 16 + rl][k0 + kb];
#pragma unroll
      for (int j = 0; j < 4; ++j) {
        acc[0][j] = __builtin_amdgcn_mfma_f32_16x16x32_bf16(af0, bfr[j], acc[0][j], 0, 0, 0);
        acc[1][j] = __builtin_amdgcn_mfma_f32_16x16x32_bf16(af1, bfr[j], acc[1][j], 0, 0, 0);
      }
    }

    if (ct < 4) {
      // store C tile (bf16)
#pragma unroll
      for (int i = 0; i < 2; ++i)
#pragma unroll
        for (int j = 0; j < 4; ++j) {
          int gc = col0 + wc * 64 + j * 16 + rl;
#pragma unroll
          for (int reg = 0; reg < 4; ++reg) {
            int gr = row0 + wr * 32 + i * 16 + g * 4 + reg;
            Cb[(size_t)gr * 512 + gc] = f2bu(acc[i][j][reg]);
          }
        }
      // per-row dot with v1 (and v2 for nf) over this head's 128 cols
      int npass = v2 ? 2 : 1;
      for (int pass = 0; pass < npass; ++pass) {
        const float* v = pass ? v2 : v1;
        float ce[4];
#pragma unroll
        for (int j = 0; j < 4; ++j) ce[j] = v[col0 + wc * 64 + j * 16 + rl];
        float p[2][4];
#pragma unroll
        for (int i = 0; i < 2; ++i)
#pragma unroll
          for (int reg = 0; reg < 4; ++reg) {
            float s = 0.f;
#pragma unroll
            for (int j = 0; j < 4; ++j) s += acc[i][j][reg] * ce[j];
            p[i][reg] = s;
          }
#pragma unroll
        for (int m = 1; m < 16; m <<= 1)
#pragma unroll
          for (int i = 0; i < 2; ++i)
#pragma unroll
            for (int reg = 0; reg < 4; ++reg)
              p[i][reg] += __shfl_xor(p[i][reg], m);
        if (rl == 0) {
#pragma unroll
          for (int i = 0; i < 2; ++i)
#pragma unroll
            for (int reg = 0; reg < 4; ++reg)
              sered[wc][wr * 32 + i * 16 + g * 4 + reg] = p[i][reg];
        }
        __syncthreads();
        if (tid < 64) {
          float* o = pass ? o2 : o1;
          o[(size_t)(row0 + tid) * 4 + ct] = sered[0][tid] + sered[1][tid];
        }
        __syncthreads();
      }
    } else {
      // ef tiles 4..6: relu + per-batch column sums -> esum
#pragma unroll
      for (int j = 0; j < 4; ++j) {
        float s = 0.f;
#pragma unroll
        for (int i = 0; i < 2; ++i)
#pragma unroll
          for (int reg = 0; reg < 4; ++reg) s += fmaxf(acc[i][j][reg], 0.f);
        red[wr * 4 + g][wc * 64 + j * 16 + rl] = s;
      }
      __syncthreads();
      if (tid < 128) {
        float s = 0.f;
#pragma unroll
        for (int y = 0; y < 8; ++y) s += red[y][tid];
        int c = col0 - 512 + tid;
        if (c < 300) atomicAdd(&esum[(size_t)(row0 >> 10) * 300 + c], s);
      }
      __syncthreads();
    }
  }
}

// ---------- small-M GEMM (M=64): out += A[64][K] @ W[K][N], split-K atomics ----------
__global__ __launch_bounds__(256) void gemm_small(
    const float* __restrict__ A, int lda, const float* __restrict__ W,
    int N, int K, int ldo, float* __restrict__ out) {
  __shared__ float As[64][256];
  int tid = threadIdx.x;
  int k0 = blockIdx.y * 256;
  int kt = min(256, K - k0);
  int col = blockIdx.x * 64 + (tid & 63);
  int bg = tid >> 6;
  int nseg = kt >> 2;
  for (int s = tid; s < 64 * nseg; s += 256) {
    int r = s / nseg, kq = s - r * nseg;
    *(float4*)&As[r][kq << 2] = *(const float4*)&A[(size_t)r * lda + k0 + (kq << 2)];
  }
  __syncthreads();
  float acc[16];
#pragma unroll
  for (int i = 0; i < 16; ++i) acc[i] = 0.f;
  if (col < N) {
    for (int k = 0; k < kt; k += 4) {
      float w0 = W[(size_t)(k0 + k) * N + col];
      float w1 = W[(size_t)(k0 + k + 1) * N + col];
      float w2 = W[(size_t)(k0 + k + 2) * N + col];
      float w3 = W[(size_t)(k0 + k + 3) * N + col];
#pragma unroll
      for (int bi = 0; bi < 16; ++bi) {
        float4 a4 = *(const float4*)&As[bg * 16 + bi][k];
        acc[bi] = fmaf(a4.x, w0, fmaf(a4.y, w1, fmaf(a4.z, w2, fmaf(a4.w, w3, acc[bi]))));
      }
    }
#pragma unroll
    for (int bi = 0; bi < 16; ++bi)
      atomicAdd(&out[(size_t)(bg * 16 + bi) * ldo + col], acc[bi]);
  }
}

// ---------- LSTM step (packed W; 128-thread blocks, 256 blocks fill all CUs) ----------
__global__ __launch_bounds__(128) void k_lstm3(
    const float* __restrict__ Wp, const float* __restrict__ xproj,
    const float* __restrict__ bls, const int* __restrict__ qmask,
    const float* __restrict__ h_in, float* __restrict__ h_out, float* __restrict__ c, int t) {
  __shared__ float hs[4][512];
  int tid = threadIdx.x;
  int j = blockIdx.x * 32 + (tid & 31);
  int bq = tid >> 5;                        // 0..3
  int b = blockIdx.y * 4 + bq;
  for (int i = tid; i < 2048; i += 128)
    hs[i >> 9][i & 511] = h_in[(size_t)(blockIdx.y * 4 + (i >> 9)) * 512 + (i & 511)];
  __syncthreads();
  float a0 = 0.f, a1 = 0.f, a2 = 0.f, a3 = 0.f;
#pragma unroll 8
  for (int k = 0; k < 512; ++k) {
    float hv = hs[bq][k];
    float4 w = *(const float4*)&Wp[(size_t)k * 2048 + j * 4];
    a0 = fmaf(hv, w.x, a0);
    a1 = fmaf(hv, w.y, a1);
    a2 = fmaf(hv, w.z, a2);
    a3 = fmaf(hv, w.w, a3);
  }
  size_t xb = ((size_t)b * SS + t) * 2048;
  float4 xp = *(const float4*)&xproj[xb + j * 4];
  float gi = a0 + xp.x + bls[j];
  float gf = a1 + xp.y + bls[512 + j];
  float gg = a2 + xp.z + bls[1024 + j];
  float go = a3 + xp.w + bls[1536 + j];
  float si = 1.f / (1.f + __expf(-gi));
  float sf = 1.f / (1.f + __expf(-gf));
  float so = 1.f / (1.f + __expf(-go));
  float tg = 2.f / (1.f + __expf(-2.f * gg)) - 1.f;
  int idx = b * 512 + j;
  float cold = c[idx];
  float cn = sf * cold + si * tg;
  float hn = so * (2.f / (1.f + __expf(-2.f * cn)) - 1.f);
  if (qmask[b * SS + t] > 0) { c[idx] = cn; h_out[idx] = hn; }
  else h_out[idx] = h_in[idx];
}

// ---------- CSR ----------
__global__ __launch_bounds__(256) void k_prep(const int* __restrict__ src, const int* __restrict__ dst,
    int* __restrict__ sg, int* __restrict__ dg, int* __restrict__ counts) {
  int i = blockIdx.x * 256 + threadIdx.x;
  int b = i >> 10;
  sg[i] = (b << 8) + src[i];
  int dgl = (b << 8) + dst[i];
  dg[i] = dgl;
  atomicAdd(&counts[dgl], 1);
}

__global__ __launch_bounds__(256) void k_scan(const int* __restrict__ counts, int* __restrict__ rs) {
  __shared__ int sc[256];
  int b = blockIdx.x, tid = threadIdx.x;
  int v = counts[b * 256 + tid];
  sc[tid] = v;
  __syncthreads();
  for (int off = 1; off < 256; off <<= 1) {
    int add = (tid >= off) ? sc[tid - off] : 0;
    __syncthreads();
    sc[tid] += add;
    __syncthreads();
  }
  rs[b * 256 + tid] = b * 1024 + sc[tid] - v;
}

__global__ __launch_bounds__(256) void k_scatter(const int* __restrict__ dg, const int* __restrict__ rs,
    int* __restrict__ fill, int* __restrict__ elist) {
  int i = blockIdx.x * 256 + threadIdx.x;
  int d = dg[i];
  int pos = rs[d] + atomicAdd(&fill[d], 1);
  elist[pos] = i;
}

// ---------- logits / softmax / aggregate ----------
__global__ __launch_bounds__(256) void k_logit(const int* __restrict__ sg, const int* __restrict__ dg,
    const float* __restrict__ ssrc, const float* __restrict__ sdst,
    const float* __restrict__ se, float* __restrict__ lg) {
  int i = blockIdx.x * 256 + threadIdx.x;
  int e = i >> 2, h = i & 3;
  float x = ssrc[sg[e] * 4 + h] + sdst[dg[e] * 4 + h] + se[i];
  lg[i] = x > 0.f ? x : 0.2f * x;
}

__global__ __launch_bounds__(256) void k_soft(const int* __restrict__ counts, const int* __restrict__ rs,
    const int* __restrict__ elist, float* __restrict__ lg) {
  int id = blockIdx.x * 256 + threadIdx.x;
  int n = id >> 2, h = id & 3;
  int deg = counts[n];
  if (deg == 0) return;
  int st = rs[n];
  float m = -1e30f;
  for (int i = 0; i < deg; ++i) { int e = elist[st + i]; m = fmaxf(m, lg[e * 4 + h]); }
  float s = 0.f;
  for (int i = 0; i < deg; ++i) {
    int e = elist[st + i];
    float p = __expf(lg[e * 4 + h] - m);
    lg[e * 4 + h] = p;
    s += p;
  }
  float inv = 1.f / (s + 1e-9f);
  for (int i = 0; i < deg; ++i) { int e = elist[st + i]; lg[e * 4 + h] *= inv; }
}

__global__ __launch_bounds__(256) void k_agg(const int* __restrict__ counts, const int* __restrict__ rs,
    const int* __restrict__ elist, const int* __restrict__ sg, const float* __restrict__ lg,
    const u16* __restrict__ hfeat, const u16* __restrict__ rfeat, u16* __restrict__ nout) {
  int n = blockIdx.x;
  int deg = counts[n], st = rs[n];
  int c1 = threadIdx.x, c2 = threadIdx.x + 256;
  float a1 = 0.f, a2 = 0.f;
  for (int i = 0; i < deg; ++i) {
    int e = elist[st + i];
    int s = sg[e];
    float al1 = lg[e * 4 + (c1 >> 7)], al2 = lg[e * 4 + (c2 >> 7)];
    a1 += al1 * (bf(hfeat[(size_t)s * 512 + c1]) + bf(rfeat[(size_t)e * 512 + c1]));
    a2 += al2 * (bf(hfeat[(size_t)s * 512 + c2]) + bf(rfeat[(size_t)e * 512 + c2]));
  }
  a1 = a1 > 0.f ? a1 : __expf(a1) - 1.f;
  a2 = a2 > 0.f ? a2 : __expf(a2) - 1.f;
  nout[(size_t)n * 512 + c1] = f2bu(a1);
  nout[(size_t)n * 512 + c2] = f2bu(a2);
}

__global__ __launch_bounds__(512) void k_nodesum(const u16* __restrict__ nout, float* __restrict__ nsum) {
  int b = blockIdx.x, col = threadIdx.x;
  float s = 0.f;
  for (int n = 0; n < 256; ++n) s += bf(nout[(size_t)((b << 8) + n) * 512 + col]);
  nsum[b * 512 + col] = s;
}

// ---------- launch ----------
extern "C" void kernel_launch(void* const* d_in, const int* in_sizes, int n_in,
                              void* d_out, int out_size, void* d_ws, size_t ws_size,
                              hipStream_t stream) {
  const int*   question   = (const int*)d_in[0];
  const int*   qmask      = (const int*)d_in[1];
  const int*   node_toks  = (const int*)d_in[2];
  const int*   edge_toks  = (const int*)d_in[3];
  const int*   src_ids    = (const int*)d_in[4];
  const int*   dst_ids    = (const int*)d_in[5];
  const float* word_emb   = (const float*)d_in[6];
  const float* W_ih       = (const float*)d_in[7];
  const float* W_hh       = (const float*)d_in[8];
  const float* b_lstm     = (const float*)d_in[9];
  const float* W_node     = (const float*)d_in[10];
  const float* W_rel      = (const float*)d_in[11];
  const float* a_src      = (const float*)d_in[12];
  const float* a_dst      = (const float*)d_in[13];
  const float* a_edge     = (const float*)d_in[14];
  const float* W_edge_upd = (const float*)d_in[15];
  const float* W_qnode    = (const float*)d_in[16];
  const float* b_qnode    = (const float*)d_in[17];
  const float* W_qedge    = (const float*)d_in[18];
  const float* b_qedge    = (const float*)d_in[19];
  const float* W_edge_prj = (const float*)d_in[20];
  const float* b_edge_prj = (const float*)d_in[21];
  const float* W_mid      = (const float*)d_in[22];
  const float* b_mid      = (const float*)d_in[23];
  const float* W_pre      = (const float*)d_in[24];
  const float* b_pre      = (const float*)d_in[25];
  float* outp = (float*)d_out;

  char* ws = (char*)d_ws;
  int*   counts = (int*)(ws + O_COUNTS);
  int*   fill   = (int*)(ws + O_FILL);
  float* esum   = (float*)(ws + O_ESUM);
  float* h0     = (float*)(ws + O_H0);
  float* cst    = (float*)(ws + O_C);
  float* h1     = (float*)(ws + O_H1);
  float* xproj  = (float*)(ws + O_XPROJ);
  u16*   btn    = (u16*)(ws + O_BT_NODE);
  u16*   btr    = (u16*)(ws + O_BT_REL);
  u16*   bte    = (u16*)(ws + O_BT_EDGE);
  u16*   nf     = (u16*)(ws + O_NF);
  u16*   ef     = (u16*)(ws + O_EF);
  u16*   hfeat  = (u16*)(ws + O_HFEAT);
  u16*   rfeat  = (u16*)(ws + O_RFEAT);
  float* Wp     = (float*)(ws + O_RFEAT);   // packed W_hh, dead before rfeat is written
  float* ssrc   = (float*)(ws + O_SSRC);
  float* sdst   = (float*)(ws + O_SDST);
  float* se     = (float*)(ws + O_SE);
  int*   sg     = (int*)(ws + O_SG);
  int*   dg     = (int*)(ws + O_DG);
  int*   rs     = (int*)(ws + O_RS);
  int*   elist  = (int*)(ws + O_ELIST);
  float* lg     = (float*)(ws + O_LG);
  u16*   nout   = (u16*)(ws + O_NOUT);
  float* nsum   = (float*)(ws + O_NSUM);
  float* qn     = (float*)(ws + O_QN);
  float* qe     = (float*)(ws + O_QE);
  float* qcat   = (float*)(ws + O_QCAT);
  float* midb   = (float*)(ws + O_MID);

  // 1. zero accumulator span
  k_zero<<<128, 256, 0, stream>>>((float*)ws, (int)(Z_BYTES / 4));
  // 2. phrase features
  k_feat<<<BNN / 4, 256, 0, stream>>>(node_toks, word_emb, nf);
  k_feat<<<BEE / 4, 256, 0, stream>>>(edge_toks, word_emb, ef);
  // 3. pack W_hh; xproj = emb(question) @ W_ih (gate-interleaved)
  k_packW<<<1024, 256, 0, stream>>>(W_hh, Wp);
  gemm_f32<<<dim3(16, 12), 256, 0, stream>>>(word_emb, DD, question, W_ih, 2048, DD, xproj, 1);
  // 4. LSTM (final h in h0)
  for (int t = 0; t < SS; ++t) {
    const float* hin = (t & 1) ? h1 : h0;
    float* hout = (t & 1) ? h0 : h1;
    k_lstm3<<<dim3(16, 16), 128, 0, stream>>>(Wp, xproj, b_lstm, qmask, hin, hout, cst, t);
  }
  // 5. weight transposes
  k_trans<<<dim3(16, 10), 256, 0, stream>>>(W_node, 512, 512, btn);
  k_trans<<<dim3(16, 10), 256, 0, stream>>>(W_rel, 512, 512, btr);
  k_trans<<<dim3(12, 10), 256, 0, stream>>>(W_edge_upd, 300, 384, bte);
  // 6. unified A-resident MFMA GEMM: ef->rfeat+se+esum, nf->hfeat+ssrc+sdst
  gemm_feat<<<1280, 256, 0, stream>>>(ef, nf, btr, btn, rfeat, hfeat,
                                      a_edge, a_src, a_dst, se, ssrc, sdst, esum);
  // 7. CSR by dst
  k_prep<<<256, 256, 0, stream>>>(src_ids, dst_ids, sg, dg, counts);
  k_scan<<<64, 256, 0, stream>>>(counts, rs);
  k_scatter<<<256, 256, 0, stream>>>(dg, rs, fill, elist);
  // 8. logits -> softmax -> aggregate
  k_logit<<<1024, 256, 0, stream>>>(sg, dg, ssrc, sdst, se, lg);
  k_soft<<<256, 256, 0, stream>>>(counts, rs, elist, lg);
  k_agg<<<BNN, 256, 0, stream>>>(counts, rs, elist, sg, lg, hfeat, rfeat, nout);
  k_nodesum<<<64, 512, 0, stream>>>(nout, nsum);
  // 9. fusion head
  k_binit<<<dim3(2, 64), 256, 0, stream>>>(b_qnode, nsum, qn, 512, 512, 512);
  k_binit<<<dim3(2, 64), 256, 0, stream>>>(b_qedge, esum, qe, 300, 300, 300);
  gemm_small<<<dim3(8, 2), 256, 0, stream>>>(h0, 512, W_qnode, 512, 512, 512, qn);
  gemm_small<<<dim3(5, 2), 256, 0, stream>>>(h0, 512, W_qedge, 300, 512, 300, qe);
  k_binit<<<dim3(2, 64), 256, 0, stream>>>(b_edge_prj, nullptr, qcat, 512, 1024, 0);
  k_binit<<<dim3(2, 64), 256, 0, stream>>>(nullptr, qn, qcat + 512, 512, 1024, 512);
  gemm_small<<<dim3(8, 2), 256, 0, stream>>>(qe, 300, W_edge_prj, 512, 300, 1024, qcat);
  k_binit<<<dim3(6, 64), 256, 0, stream>>>(b_mid, nullptr, midb, 1536, 1536, 0);
  gemm_small<<<dim3(24, 4), 256, 0, stream>>>(qcat, 1024, W_mid, 1536, 1024, 1536, midb);
  k_binit<<<dim3(12, 64), 256, 0, stream>>>(b_pre, nullptr, outp, NAA, NAA, 0);
  gemm_small<<<dim3(47, 6), 256, 0, stream>>>(midb, 1536, W_pre, NAA, 1536, NAA, outp);
}